// Round 12
// baseline (330.102 us; speedup 1.0000x reference)
//
#include <hip/hip_runtime.h>
#include <hip/hip_bf16.h>

// Problem constants
#define NB 256
#define NACT 21
#define NA 8192
#define NE 262144
#define HCAP 64      // per-half CSR capacity (2 sub-counters per dst)
#define LOG2E 1.44269504f

#if __has_builtin(__builtin_amdgcn_exp2f)
#define EXP2F(x) __builtin_amdgcn_exp2f(x)
#else
#define EXP2F(x) exp2f(x)
#endif

typedef __attribute__((ext_vector_type(8))) short short8;
typedef __attribute__((ext_vector_type(4))) float float4v;

__device__ inline float wsum64(float v) {
#pragma unroll
  for (int m = 32; m > 0; m >>= 1) v += __shfl_xor(v, m, 64);
  return v;
}

__device__ inline unsigned short f2bf(float f) {
  union { __hip_bfloat16 h; unsigned short u; } cv;
  cv.h = __float2bfloat16(f);
  return cv.u;
}

// ---------------- k_init: zero cnt2 + action passthrough ----------------
__global__ void k_init(const int* action, int* cnt2, float* out) {
  int i = blockIdx.x * 256 + threadIdx.x;  // 64*256 = 16384
  if (i < 2 * NA) cnt2[i] = 0;
  if (i < NB) out[i] = (float)action[i];
}

// ---------- k_pc: conv (blocks 0..511, half-image each) || prep (512..767) ----------
__global__ __launch_bounds__(512, 4) void k_pc(
    const float* __restrict__ x, const int* __restrict__ edges,
    const float* __restrict__ c1w, const float* __restrict__ c1b,
    const float* __restrict__ c2w, const float* __restrict__ c2b,
    const float* __restrict__ fcw, const float* __restrict__ g2w,
    const float* __restrict__ g2b,
    unsigned short* h1024bf, unsigned short* fcwbf, unsigned short* w2t,
    float* wpart, int* cnt2, int* csr) {
  union SM {
    struct { float xs[845]; float w1s[1440]; float c1s[1152]; float w2s[32 * 73]; } cv;
    struct { float red[32][17]; float b2s[32]; } w2;
  };
  __shared__ __align__(16) union SM sm;
  int t = threadIdx.x, blk = blockIdx.x;

  if (blk >= 512) {  // ---- prep ----
    int pb = blk - 512;  // 0..255
    {  // CSR with 2 sub-counters: first 128K edges -> half 0, rest -> half 1
      int e = pb * 512 + t;
      int s = edges[2 * e], d = edges[2 * e + 1];
      int slot = atomicAdd(&cnt2[2 * d], 1);
      if (slot < HCAP) csr[d * 128 + slot] = s;
      int e2 = e + 131072;
      s = edges[2 * e2]; d = edges[2 * e2 + 1];
      slot = atomicAdd(&cnt2[2 * d + 1], 1);
      if (slot < HCAP) csr[d * 128 + HCAP + slot] = s;
    }
    {  // fcw -> bf16: 4 floats per thread
      int base = (pb * 512 + t) * 4;
      float4 v = *(const float4*)&fcw[base];
      fcwbf[base + 0] = f2bf(v.x); fcwbf[base + 1] = f2bf(v.y);
      fcwbf[base + 2] = f2bf(v.z); fcwbf[base + 3] = f2bf(v.w);
    }
    {  // W2: block owns 32 cols; w2t[j][k] = W2[k][j] bf16; column/bias partials
      int jj = t >> 4, k = t & 15;
      int j = pb * 32 + jj;
      float w = g2w[k * 8192 + j];
      w2t[j * 16 + k] = f2bf(w);
      sm.w2.red[jj][k] = w;
      if (t < 32) sm.w2.b2s[t] = g2b[pb * 32 + t];
      __syncthreads();
      if (t < 16) {
        float s = 0.0f;
#pragma unroll
        for (int q = 0; q < 32; q++) s += sm.w2.red[q][t];
        wpart[pb * 17 + t] = s;
      } else if (t == 16) {
        float s = 0.0f;
#pragma unroll
        for (int q = 0; q < 32; q++) s += sm.w2.b2s[q];
        wpart[pb * 17 + 16] = s;
      }
    }
    return;
  }
  // ---- conv: 2 blocks per image, each does 32 of 64 output channels ----
  int img = blk >> 1, half = blk & 1;
  for (int i = t; i < 845; i += 512) sm.cv.xs[i] = x[img * 845 + i];
  for (int i = t; i < 1440; i += 512) sm.cv.w1s[i] = c1w[i];
  __syncthreads();
  for (int idx = t; idx < 1152; idx += 512) {  // conv1 (computed by both halves)
    int oc = idx / 36, p = idx - oc * 36;
    int oy = p / 6, ox = p - oy * 6;
    float acc = c1b[oc];
    const float* wp = &sm.cv.w1s[oc * 45];
#pragma unroll
    for (int ic = 0; ic < 5; ic++)
#pragma unroll
      for (int ky = 0; ky < 3; ky++)
#pragma unroll
        for (int kx = 0; kx < 3; kx++)
          acc += sm.cv.xs[ic * 169 + (oy * 2 + ky) * 13 + ox * 2 + kx] * wp[ic * 9 + ky * 3 + kx];
    sm.cv.c1s[idx] = fmaxf(acc, 0.0f);
  }
  int p = t & 15, ocl = t >> 4;        // 32 local ocs x 16 pixels
  int oc = half * 32 + ocl;
  int oy = p >> 2, ox = p & 3;
  float a0 = c2b[oc];
  for (int icb = 0; icb < 32; icb += 8) {
    __syncthreads();
    for (int i = t; i < 2304; i += 512) {  // stage 32 ocs x 72 weights
      int o = i / 72, r = i - o * 72;
      sm.cv.w2s[o * 73 + r] = c2w[(half * 32 + o) * 288 + icb * 9 + r];
    }
    __syncthreads();
#pragma unroll
    for (int ic = 0; ic < 8; ic++)
#pragma unroll
      for (int ky = 0; ky < 3; ky++)
#pragma unroll
        for (int kx = 0; kx < 3; kx++)
          a0 += sm.cv.c1s[(icb + ic) * 36 + (oy + ky) * 6 + ox + kx] *
                sm.cv.w2s[ocl * 73 + ic * 9 + ky * 3 + kx];
  }
  h1024bf[img * 1024 + oc * 16 + p] = f2bf(fmaxf(a0, 0.0f));
}

// ---------------- k_fc: FC via bf16 MFMA (1 tile/block, K-split 4) + dinv/xs2 ----------------
__global__ __launch_bounds__(256, 4) void k_fc(
    const int* __restrict__ cnt2, const float* __restrict__ x_msg,
    const unsigned short* __restrict__ h1024bf, const unsigned short* __restrict__ fcwbf,
    const float* __restrict__ fcb, float* hidden, float* dinv, float* xs2) {
  __shared__ float red[4][256];
  int t = threadIdx.x, blk = blockIdx.x;
  int wave = t >> 6, lane = t & 63;
  if (blk < 32) {
    int i = blk * 256 + t;
    float d = rsqrtf((float)(cnt2[2 * i] + cnt2[2 * i + 1]) + 1.0f);
    dinv[i] = d;
    xs2[i] = d * x_msg[i];
  }
  int tr = blk >> 5, tc = blk & 31;  // 16 row-tiles x 32 col-tiles
  int m = lane & 15, quad = lane >> 4;
  const unsigned short* ap = &h1024bf[(tr * 16 + m) * 1024 + wave * 256 + quad * 8];
  const unsigned short* bp = &fcwbf[(tc * 16 + m) * 1024 + wave * 256 + quad * 8];
  float4v acc = {0.0f, 0.0f, 0.0f, 0.0f};
#pragma unroll
  for (int i = 0; i < 8; i++) {
    short8 a = *(const short8*)(ap + i * 32);
    short8 b = *(const short8*)(bp + i * 32);
    acc = __builtin_amdgcn_mfma_f32_16x16x32_bf16(a, b, acc, 0, 0, 0);
  }
#pragma unroll
  for (int r = 0; r < 4; r++) red[wave][(quad * 4 + r) * 16 + m] = acc[r];
  __syncthreads();
  {
    float s = red[0][t] + red[1][t] + red[2][t] + red[3][t];
    int gr = tr * 16 + (t >> 4);
    int gc = tc * 16 + (t & 15);
    hidden[gr * 512 + gc] = fmaxf(s + fcb[gc], 0.0f);
  }
}

// ---------------- k_he: head (blocks 0..63) | enc (blocks 64..511) ----------------
__global__ __launch_bounds__(512, 2) void k_he(
    const float* __restrict__ hidden, const float* __restrict__ muw,
    const float* __restrict__ mub, const float* __restrict__ msgw,
    const float* __restrict__ msgb, const float* __restrict__ dinv,
    float* es2, float* out) {
  __shared__ float muT[10752];
  __shared__ float hrows[2048];
  int t = threadIdx.x, blk = blockIdx.x;
  int wave = t >> 6, lane = t & 63;
  if (blk < 64) {
    int b0 = blk * 4;
    for (int i = t; i < 10752; i += 512) {
      int a = i >> 9, k = i & 511;
      muT[k * 21 + a] = muw[i];
    }
    for (int i = t; i < 2048; i += 512) hrows[i] = hidden[b0 * 512 + i];
    __syncthreads();
    if (wave < 4) {
      int b = b0 + wave;
      float logit = -1e30f;
      if (lane < NACT) {
        float acc = mub[lane];
        const float* hr = &hrows[wave * 512];
        for (int k = 0; k < 512; k++) acc += hr[k] * muT[k * 21 + lane];
        logit = acc;
      }
      float m = logit;
#pragma unroll
      for (int s = 32; s > 0; s >>= 1) m = fmaxf(m, __shfl_xor(m, s, 64));
      float e = (lane < NACT) ? __expf(logit - m) : 0.0f;
      float se = wsum64(e);
      float swl = wsum64(e * logit);
      float lse = m + __logf(se);
      if (lane == 0) out[8704 + b] = lse - swl / se;  // entropy
      int act = (int)out[b];                          // action (from k_init)
      if (lane == act) out[8448 + b] = logit - lse;   // log_prob
    }
  } else {  // enc: es2[j] = dinv[j] * (hidden[0].msg_w[j] + msgb[j])
    int wg = (blk - 64) * 8 + wave;  // 0..3583
    for (int j = wg; j < NA; j += 3584) {
      const float* wp = &msgw[j * 512 + lane * 8];
      float4 w0 = *(const float4*)(wp);
      float4 w1 = *(const float4*)(wp + 4);
      float4 h0 = *(const float4*)&hidden[lane * 8];
      float4 h1 = *(const float4*)&hidden[lane * 8 + 4];
      float s = w0.x * h0.x + w0.y * h0.y + w0.z * h0.z + w0.w * h0.w +
                w1.x * h1.x + w1.y * h1.y + w1.z * h1.z + w1.w * h1.w;
      s = wsum64(s);
      if (lane == 0) es2[j] = dinv[j] * (s + msgb[j]);
    }
  }
}

// ---------------- k_g1: GCN1 gather (2 rows per wave, two CSR halves) ----------------
__global__ __launch_bounds__(512, 4) void k_g1(
    const int* __restrict__ cnt2, const int* __restrict__ csr,
    const float* __restrict__ dinv, const float* __restrict__ xs2,
    const float* __restrict__ es2, const float* __restrict__ g1w,
    const float* __restrict__ g1b, float* gbuf2) {
  int t = threadIdx.x, blk = blockIdx.x;
  int wave = t >> 6, lane = t & 63;
  int wg = blk * 8 + wave;  // 0..4095
#pragma unroll
  for (int rr = 0; rr < 2; rr++) {
    int i = wg * 2 + rr;
    int ci0 = min(cnt2[2 * i], HCAP), ci1 = min(cnt2[2 * i + 1], HCAP);
    float di = dinv[i];
    float a0 = 0.0f, a1 = 0.0f;
    if (lane < ci0) {
      int s = csr[i * 128 + lane];
      a0 += xs2[s];
      a1 += es2[s];
    }
    if (lane < ci1) {
      int s = csr[i * 128 + HCAP + lane];
      a0 += xs2[s];
      a1 += es2[s];
    }
    // self-loop coeff di^2: di*(sum_s dinv[s]x[s] + dinv[i]x[i])
    float f0 = (wsum64(a0) + xs2[i]) * di;
    float f1 = (wsum64(a1) + es2[i]) * di;
    if (lane < 16) {
      float gv = fmaxf(f0 * g1w[lane] + f1 * g1w[16 + lane] + g1b[lane], 0.0f);
      gbuf2[i * 16 + lane] = di * gv;
    }
  }
}

// ---------------- k_msg: GCN2 gather + wstats + MFMA scores + sum-exp ----------------
__global__ __launch_bounds__(512, 2) void k_msg(
    const int* __restrict__ cnt2, const int* __restrict__ csr,
    const float* __restrict__ dinv, const float* __restrict__ gbuf2,
    const float* __restrict__ wpart, const unsigned short* __restrict__ w2t,
    const float* __restrict__ g2b, float* out) {
  __shared__ __align__(16) unsigned short vbf[512];
  __shared__ float vf[512];
  __shared__ float pl[4096];
  __shared__ float sl[256];
  __shared__ float wp[16][17];
  __shared__ float wsf[17];
  int t = threadIdx.x, blk = blockIdx.x;
  int wave = t >> 6, lane = t & 63;
  int rowbase = blk * 32;
  {  // gather 32 V rows: 8 waves x 4 rows; lanes = 4 edge-groups x 16 cols
    int eq = lane >> 4, c = lane & 15;
#pragma unroll
    for (int rr = 0; rr < 4; rr++) {
      int il = wave * 4 + rr;
      int i = rowbase + il;
      int ci0 = min(cnt2[2 * i], HCAP), ci1 = min(cnt2[2 * i + 1], HCAP);
      float di = dinv[i];
      float acc = (eq == 0) ? gbuf2[i * 16 + c] : 0.0f;  // self: di*(...+gbuf2[i]) = di^2*g_i
      for (int e = eq; e < ci0; e += 4) {
        int s = csr[i * 128 + e];
        acc += gbuf2[s * 16 + c];
      }
      for (int e = eq; e < ci1; e += 4) {
        int s = csr[i * 128 + HCAP + e];
        acc += gbuf2[s * 16 + c];
      }
      acc *= di;
      acc += __shfl_xor(acc, 16, 64);
      acc += __shfl_xor(acc, 32, 64);
      if (eq == 0) {
        vf[il * 16 + c] = acc;
        vbf[il * 16 + c] = f2bf(acc * LOG2E);  // pre-scale for exp2
      }
    }
  }
  __syncthreads();
  if (t < 272) {  // wstats reduce from 256 per-block partials
    int bq = t / 17, k = t - bq * 17;
    float s = 0.0f;
    for (int b = bq; b < 256; b += 16) s += wpart[b * 17 + k];
    wp[bq][k] = s;
  }
  __syncthreads();
  if (t < 17) {
    float s = 0.0f;
#pragma unroll
    for (int q = 0; q < 16; q++) s += wp[q][t];
    wsf[t] = s;
  }
  __syncthreads();
  float myMean = 0.0f;
  if (t < 32) {
    float dot = 0.0f;
#pragma unroll
    for (int c = 0; c < 16; c++) dot += vf[t * 16 + c] * wsf[c];
    myMean = (dot + wsf[16]) * (1.0f / 8192.0f);
  }
  {  // scores via MFMA (log2e-scaled) + exp2; each wave owns a 1024-col slice
    int quad = lane >> 4, n = lane & 15;
    int k8 = quad * 8;
    short8 za = {0, 0, 0, 0, 0, 0, 0, 0};
    short8 a1 = za, a2 = za;
    if (quad < 2) {  // K padded 16->32
      a1 = *(const short8*)&vbf[n * 16 + k8];
      a2 = *(const short8*)&vbf[(16 + n) * 16 + k8];
    }
    float sacc[8];
#pragma unroll
    for (int q = 0; q < 8; q++) sacc[q] = 0.0f;
    int colb = wave * 1024 + n;
    for (int tp = 0; tp < 64; tp += 2) {
      int col1 = colb + tp * 16;
      int col2 = col1 + 16;
      short8 b1 = za, b2 = za;
      if (quad < 2) {
        b1 = *(const short8*)&w2t[col1 * 16 + k8];
        b2 = *(const short8*)&w2t[col2 * 16 + k8];
      }
      float bb1 = g2b[col1] * LOG2E, bb2 = g2b[col2] * LOG2E;
      float4v c1 = {bb1, bb1, bb1, bb1};
      float4v c2 = {bb2, bb2, bb2, bb2};
      float4v s11 = __builtin_amdgcn_mfma_f32_16x16x32_bf16(a1, b1, c1, 0, 0, 0);
      float4v s21 = __builtin_amdgcn_mfma_f32_16x16x32_bf16(a2, b1, c1, 0, 0, 0);
      float4v s12 = __builtin_amdgcn_mfma_f32_16x16x32_bf16(a1, b2, c2, 0, 0, 0);
      float4v s22 = __builtin_amdgcn_mfma_f32_16x16x32_bf16(a2, b2, c2, 0, 0, 0);
#pragma unroll
      for (int r = 0; r < 4; r++) {
        sacc[r]     += EXP2F(s11[r]) + EXP2F(s12[r]);
        sacc[4 + r] += EXP2F(s21[r]) + EXP2F(s22[r]);
      }
    }
#pragma unroll
    for (int q = 0; q < 8; q++) {
      int rl = (q >> 2) * 16 + quad * 4 + (q & 3);  // C/D row = quad*4+reg (+16 for A2)
      pl[rl * 128 + wave * 16 + n] = sacc[q];
    }
  }
  __syncthreads();
  if (t < 256) {
    int r = t >> 3, seg = t & 7;
    int base = r * 128 + seg * 16;
    float ll = 0.0f;
#pragma unroll
    for (int i = 0; i < 16; i++) ll += pl[base + i];
    sl[r * 8 + seg] = ll;
  }
  __syncthreads();
  if (t < 32) {
    float ll = 0.0f;
#pragma unroll
    for (int i = 0; i < 8; i++) ll += sl[t * 8 + i];
    out[256 + rowbase + t] = myMean - __logf(ll);  // ll = sum exp(s)
  }
}

extern "C" void kernel_launch(void* const* d_in, const int* in_sizes, int n_in,
                              void* d_out, int out_size, void* d_ws, size_t ws_size,
                              hipStream_t stream) {
  const float* x     = (const float*)d_in[0];
  const float* x_msg = (const float*)d_in[1];
  const int*   edges = (const int*)d_in[2];
  const int*   action= (const int*)d_in[3];
  const float* c1w   = (const float*)d_in[4];
  const float* c1b   = (const float*)d_in[5];
  const float* c2w   = (const float*)d_in[6];
  const float* c2b   = (const float*)d_in[7];
  const float* fcw   = (const float*)d_in[8];
  const float* fcb   = (const float*)d_in[9];
  const float* muw   = (const float*)d_in[10];
  const float* mub   = (const float*)d_in[11];
  const float* msgw  = (const float*)d_in[12];
  const float* msgb  = (const float*)d_in[13];
  const float* g1w   = (const float*)d_in[14];
  const float* g1b   = (const float*)d_in[15];
  const float* g2w   = (const float*)d_in[16];
  const float* g2b   = (const float*)d_in[17];
  float* out = (float*)d_out;  // reference outputs are fp32

  float* ws     = (float*)d_ws;
  unsigned short* h1024bf = (unsigned short*)ws;            // 262144 bf16
  unsigned short* fcwbf   = (unsigned short*)(ws + 131072); // 524288 bf16
  float* hidden = ws + 393216;           // 131072
  float* es2    = ws + 524288;           // 8192
  float* dinv   = ws + 532480;           // 8192
  float* xs2    = ws + 540672;           // 8192
  float* gbuf2  = ws + 548864;           // 131072
  float* wpart  = ws + 679936;           // 4352
  unsigned short* w2t = (unsigned short*)(ws + 684288);     // 131072 bf16
  int*   cnt2   = (int*)(ws + 749824);   // 16384
  int*   csr    = (int*)(ws + 766208);   // 1048576  -> total ~7.3 MB

  k_init<<<64, 256, 0, stream>>>(action, cnt2, out);
  k_pc  <<<768, 512, 0, stream>>>(x, edges, c1w, c1b, c2w, c2b, fcw, g2w, g2b,
                                  h1024bf, fcwbf, w2t, wpart, cnt2, csr);
  k_fc  <<<512, 256, 0, stream>>>(cnt2, x_msg, h1024bf, fcwbf, fcb, hidden, dinv, xs2);
  k_he  <<<512, 512, 0, stream>>>(hidden, muw, mub, msgw, msgb, dinv, es2, out);
  k_g1  <<<512, 512, 0, stream>>>(cnt2, csr, dinv, xs2, es2, g1w, g1b, gbuf2);
  k_msg <<<256, 512, 0, stream>>>(cnt2, csr, dinv, gbuf2, wpart, w2t, g2b, out);
}

// Round 13
// 257.310 us; speedup vs baseline: 1.2829x; 1.2829x over previous
//
#include <hip/hip_runtime.h>
#include <hip/hip_bf16.h>

// Problem constants
#define NB 256
#define NACT 21
#define NA 8192
#define NE 262144
#define HCAP 64      // per-half CSR capacity (2 sub-counters per dst)
#define LOG2E 1.44269504f

#if __has_builtin(__builtin_amdgcn_exp2f)
#define EXP2F(x) __builtin_amdgcn_exp2f(x)
#else
#define EXP2F(x) exp2f(x)
#endif

typedef __attribute__((ext_vector_type(8))) short short8;
typedef __attribute__((ext_vector_type(4))) float float4v;

__device__ inline float wsum64(float v) {
#pragma unroll
  for (int m = 32; m > 0; m >>= 1) v += __shfl_xor(v, m, 64);
  return v;
}

__device__ inline unsigned short f2bf(float f) {
  union { __hip_bfloat16 h; unsigned short u; } cv;
  cv.h = __float2bfloat16(f);
  return cv.u;
}

// ---------------- k_init: zero cnt2 + action passthrough ----------------
__global__ void k_init(const int* action, int* cnt2, float* out) {
  int i = blockIdx.x * 256 + threadIdx.x;  // 64*256 = 16384
  if (i < 2 * NA) cnt2[i] = 0;
  if (i < NB) out[i] = (float)action[i];
}

// ---------------- k_prep: CSR (sub-counters) + fcw->bf16 + W2 prep ----------------
// Light register footprint -> safe to bound for occupancy.
__global__ __launch_bounds__(512, 4) void k_prep(
    const int* __restrict__ edges, const float* __restrict__ fcw,
    const float* __restrict__ g2w, const float* __restrict__ g2b,
    unsigned short* fcwbf, unsigned short* w2t, float* wpart, int* cnt2, int* csr) {
  __shared__ float red[16][17];
  __shared__ float b2s[16];
  int t = threadIdx.x, blk = blockIdx.x;
  {  // CSR: 1 edge per thread; half = source-half of edge list (chains halved)
    int e = blk * 512 + t;
    int half = e >> 17;  // 0 for first 131072 edges, 1 for rest
    int s = edges[2 * e], d = edges[2 * e + 1];
    int slot = atomicAdd(&cnt2[2 * d + half], 1);
    if (slot < HCAP) csr[d * 128 + half * HCAP + slot] = s;
  }
  {  // fcw -> bf16: 2 floats per thread
    int base = (blk * 512 + t) * 2;
    float2 v = *(const float2*)&fcw[base];
    fcwbf[base + 0] = f2bf(v.x);
    fcwbf[base + 1] = f2bf(v.y);
  }
  {  // W2: block owns 16 cols; w2t[j][k] = W2[k][j] bf16; column/bias partials
    if (t < 256) {
      int jj = t >> 4, k = t & 15;
      int j = blk * 16 + jj;
      float w = g2w[k * 8192 + j];
      w2t[j * 16 + k] = f2bf(w);
      red[jj][k] = w;
    }
    if (t < 16) b2s[t] = g2b[blk * 16 + t];
    __syncthreads();
    if (t < 16) {
      float s = 0.0f;
#pragma unroll
      for (int q = 0; q < 16; q++) s += red[q][t];
      wpart[blk * 17 + t] = s;
    } else if (t == 16) {
      float s = 0.0f;
#pragma unroll
      for (int q = 0; q < 16; q++) s += b2s[q];
      wpart[blk * 17 + 16] = s;
    }
  }
}

// ---------------- k_conv: 2 blocks per image, 32 output channels each ----------------
// Register-heavy: NO tight launch_bounds (spill trap — R7/R12 lesson).
__global__ __launch_bounds__(512, 2) void k_conv(
    const float* __restrict__ x, const float* __restrict__ c1w, const float* __restrict__ c1b,
    const float* __restrict__ c2w, const float* __restrict__ c2b, unsigned short* h1024bf) {
  __shared__ float xs[845];
  __shared__ float w1s[1440];
  __shared__ float c1s[1152];
  __shared__ float w2s[32 * 73];
  int t = threadIdx.x, blk = blockIdx.x;
  int img = blk >> 1, half = blk & 1;
  for (int i = t; i < 845; i += 512) xs[i] = x[img * 845 + i];
  for (int i = t; i < 1440; i += 512) w1s[i] = c1w[i];
  __syncthreads();
  for (int idx = t; idx < 1152; idx += 512) {  // conv1 (both halves compute it)
    int oc = idx / 36, p = idx - oc * 36;
    int oy = p / 6, ox = p - oy * 6;
    float acc = c1b[oc];
    const float* wp = &w1s[oc * 45];
#pragma unroll
    for (int ic = 0; ic < 5; ic++)
#pragma unroll
      for (int ky = 0; ky < 3; ky++)
#pragma unroll
        for (int kx = 0; kx < 3; kx++)
          acc += xs[ic * 169 + (oy * 2 + ky) * 13 + ox * 2 + kx] * wp[ic * 9 + ky * 3 + kx];
    c1s[idx] = fmaxf(acc, 0.0f);
  }
  int p = t & 15, ocl = t >> 4;  // 32 local ocs x 16 pixels
  int oc = half * 32 + ocl;
  int oy = p >> 2, ox = p & 3;
  float a0 = c2b[oc];
  for (int icb = 0; icb < 32; icb += 8) {
    __syncthreads();
    for (int i = t; i < 2304; i += 512) {  // stage this half's 32 ocs x 72 weights
      int o = i / 72, r = i - o * 72;
      w2s[o * 73 + r] = c2w[(half * 32 + o) * 288 + icb * 9 + r];
    }
    __syncthreads();
#pragma unroll
    for (int ic = 0; ic < 8; ic++)
#pragma unroll
      for (int ky = 0; ky < 3; ky++)
#pragma unroll
        for (int kx = 0; kx < 3; kx++)
          a0 += c1s[(icb + ic) * 36 + (oy + ky) * 6 + ox + kx] *
                w2s[ocl * 73 + ic * 9 + ky * 3 + kx];
  }
  h1024bf[img * 1024 + oc * 16 + p] = f2bf(fmaxf(a0, 0.0f));
}

// ---------------- k_fc: FC via bf16 MFMA (1 tile/block, K-split 4) + dinv/xs2 ----------------
__global__ __launch_bounds__(256, 4) void k_fc(
    const int* __restrict__ cnt2, const float* __restrict__ x_msg,
    const unsigned short* __restrict__ h1024bf, const unsigned short* __restrict__ fcwbf,
    const float* __restrict__ fcb, float* hidden, float* dinv, float* xs2) {
  __shared__ float red[4][256];
  int t = threadIdx.x, blk = blockIdx.x;
  int wave = t >> 6, lane = t & 63;
  if (blk < 32) {
    int i = blk * 256 + t;
    float d = rsqrtf((float)(cnt2[2 * i] + cnt2[2 * i + 1]) + 1.0f);
    dinv[i] = d;
    xs2[i] = d * x_msg[i];
  }
  int tr = blk >> 5, tc = blk & 31;  // 16 row-tiles x 32 col-tiles
  int m = lane & 15, quad = lane >> 4;
  const unsigned short* ap = &h1024bf[(tr * 16 + m) * 1024 + wave * 256 + quad * 8];
  const unsigned short* bp = &fcwbf[(tc * 16 + m) * 1024 + wave * 256 + quad * 8];
  float4v acc = {0.0f, 0.0f, 0.0f, 0.0f};
#pragma unroll
  for (int i = 0; i < 8; i++) {
    short8 a = *(const short8*)(ap + i * 32);
    short8 b = *(const short8*)(bp + i * 32);
    acc = __builtin_amdgcn_mfma_f32_16x16x32_bf16(a, b, acc, 0, 0, 0);
  }
#pragma unroll
  for (int r = 0; r < 4; r++) red[wave][(quad * 4 + r) * 16 + m] = acc[r];
  __syncthreads();
  {  // reduce 4 K-slices + bias + relu
    float s = red[0][t] + red[1][t] + red[2][t] + red[3][t];
    int gr = tr * 16 + (t >> 4);
    int gc = tc * 16 + (t & 15);
    hidden[gr * 512 + gc] = fmaxf(s + fcb[gc], 0.0f);
  }
}

// ---------------- k_he: head (blocks 0..63) | enc (blocks 64..511) ----------------
__global__ __launch_bounds__(512, 2) void k_he(
    const float* __restrict__ hidden, const float* __restrict__ muw,
    const float* __restrict__ mub, const float* __restrict__ msgw,
    const float* __restrict__ msgb, const float* __restrict__ dinv,
    float* es2, float* out) {
  __shared__ float muT[10752];
  __shared__ float hrows[2048];
  int t = threadIdx.x, blk = blockIdx.x;
  int wave = t >> 6, lane = t & 63;
  if (blk < 64) {
    int b0 = blk * 4;
    for (int i = t; i < 10752; i += 512) {
      int a = i >> 9, k = i & 511;
      muT[k * 21 + a] = muw[i];
    }
    for (int i = t; i < 2048; i += 512) hrows[i] = hidden[b0 * 512 + i];
    __syncthreads();
    if (wave < 4) {
      int b = b0 + wave;
      float logit = -1e30f;
      if (lane < NACT) {
        float acc = mub[lane];
        const float* hr = &hrows[wave * 512];
        for (int k = 0; k < 512; k++) acc += hr[k] * muT[k * 21 + lane];
        logit = acc;
      }
      float m = logit;
#pragma unroll
      for (int s = 32; s > 0; s >>= 1) m = fmaxf(m, __shfl_xor(m, s, 64));
      float e = (lane < NACT) ? __expf(logit - m) : 0.0f;
      float se = wsum64(e);
      float swl = wsum64(e * logit);
      float lse = m + __logf(se);
      if (lane == 0) out[8704 + b] = lse - swl / se;  // entropy
      int act = (int)out[b];                          // action (from k_init)
      if (lane == act) out[8448 + b] = logit - lse;   // log_prob
    }
  } else {  // enc: es2[j] = dinv[j] * (hidden[0].msg_w[j] + msgb[j])
    int wg = (blk - 64) * 8 + wave;  // 0..3583
    for (int j = wg; j < NA; j += 3584) {
      const float* wp = &msgw[j * 512 + lane * 8];
      float4 w0 = *(const float4*)(wp);
      float4 w1 = *(const float4*)(wp + 4);
      float4 h0 = *(const float4*)&hidden[lane * 8];
      float4 h1 = *(const float4*)&hidden[lane * 8 + 4];
      float s = w0.x * h0.x + w0.y * h0.y + w0.z * h0.z + w0.w * h0.w +
                w1.x * h1.x + w1.y * h1.y + w1.z * h1.z + w1.w * h1.w;
      s = wsum64(s);
      if (lane == 0) es2[j] = dinv[j] * (s + msgb[j]);
    }
  }
}

// ---------------- k_g1: GCN1 gather (2 rows per wave, two CSR halves) ----------------
__global__ __launch_bounds__(512, 4) void k_g1(
    const int* __restrict__ cnt2, const int* __restrict__ csr,
    const float* __restrict__ dinv, const float* __restrict__ xs2,
    const float* __restrict__ es2, const float* __restrict__ g1w,
    const float* __restrict__ g1b, float* gbuf2) {
  int t = threadIdx.x, blk = blockIdx.x;
  int wave = t >> 6, lane = t & 63;
  int wg = blk * 8 + wave;  // 0..4095
#pragma unroll
  for (int rr = 0; rr < 2; rr++) {
    int i = wg * 2 + rr;
    int ci0 = min(cnt2[2 * i], HCAP), ci1 = min(cnt2[2 * i + 1], HCAP);
    float di = dinv[i];
    float a0 = 0.0f, a1 = 0.0f;
    if (lane < ci0) {
      int s = csr[i * 128 + lane];
      a0 += xs2[s];
      a1 += es2[s];
    }
    if (lane < ci1) {
      int s = csr[i * 128 + HCAP + lane];
      a0 += xs2[s];
      a1 += es2[s];
    }
    // self-loop coeff di^2: di*(sum_s dinv[s]x[s] + dinv[i]x[i])
    float f0 = (wsum64(a0) + xs2[i]) * di;
    float f1 = (wsum64(a1) + es2[i]) * di;
    if (lane < 16) {
      float gv = fmaxf(f0 * g1w[lane] + f1 * g1w[16 + lane] + g1b[lane], 0.0f);
      gbuf2[i * 16 + lane] = di * gv;
    }
  }
}

// ---------------- k_msg: GCN2 gather + wstats + MFMA scores + sum-exp ----------------
__global__ __launch_bounds__(512, 2) void k_msg(
    const int* __restrict__ cnt2, const int* __restrict__ csr,
    const float* __restrict__ dinv, const float* __restrict__ gbuf2,
    const float* __restrict__ wpart, const unsigned short* __restrict__ w2t,
    const float* __restrict__ g2b, float* out) {
  __shared__ __align__(16) unsigned short vbf[512];
  __shared__ float vf[512];
  __shared__ float pl[4096];
  __shared__ float sl[256];
  __shared__ float wp[16][17];
  __shared__ float wsf[17];
  int t = threadIdx.x, blk = blockIdx.x;
  int wave = t >> 6, lane = t & 63;
  int rowbase = blk * 32;
  {  // gather 32 V rows: 8 waves x 4 rows; lanes = 4 edge-groups x 16 cols
    int eq = lane >> 4, c = lane & 15;
#pragma unroll
    for (int rr = 0; rr < 4; rr++) {
      int il = wave * 4 + rr;
      int i = rowbase + il;
      int ci0 = min(cnt2[2 * i], HCAP), ci1 = min(cnt2[2 * i + 1], HCAP);
      float di = dinv[i];
      float acc = (eq == 0) ? gbuf2[i * 16 + c] : 0.0f;  // self: di*(...+gbuf2[i]) = di^2*g_i
      for (int e = eq; e < ci0; e += 4) {
        int s = csr[i * 128 + e];
        acc += gbuf2[s * 16 + c];
      }
      for (int e = eq; e < ci1; e += 4) {
        int s = csr[i * 128 + HCAP + e];
        acc += gbuf2[s * 16 + c];
      }
      acc *= di;
      acc += __shfl_xor(acc, 16, 64);
      acc += __shfl_xor(acc, 32, 64);
      if (eq == 0) {
        vf[il * 16 + c] = acc;
        vbf[il * 16 + c] = f2bf(acc * LOG2E);  // pre-scale for exp2
      }
    }
  }
  __syncthreads();
  if (t < 272) {  // wstats reduce from 512 per-block partials
    int bq = t / 17, k = t - bq * 17;
    float s = 0.0f;
    for (int b = bq; b < 512; b += 16) s += wpart[b * 17 + k];
    wp[bq][k] = s;
  }
  __syncthreads();
  if (t < 17) {
    float s = 0.0f;
#pragma unroll
    for (int q = 0; q < 16; q++) s += wp[q][t];
    wsf[t] = s;
  }
  __syncthreads();
  float myMean = 0.0f;
  if (t < 32) {
    float dot = 0.0f;
#pragma unroll
    for (int c = 0; c < 16; c++) dot += vf[t * 16 + c] * wsf[c];
    myMean = (dot + wsf[16]) * (1.0f / 8192.0f);
  }
  {  // scores via MFMA (log2e-scaled) + exp2; each wave owns a 1024-col slice
    int quad = lane >> 4, n = lane & 15;
    int k8 = quad * 8;
    short8 za = {0, 0, 0, 0, 0, 0, 0, 0};
    short8 a1 = za, a2 = za;
    if (quad < 2) {  // K padded 16->32
      a1 = *(const short8*)&vbf[n * 16 + k8];
      a2 = *(const short8*)&vbf[(16 + n) * 16 + k8];
    }
    float sacc[8];
#pragma unroll
    for (int q = 0; q < 8; q++) sacc[q] = 0.0f;
    int colb = wave * 1024 + n;
    for (int tp = 0; tp < 64; tp += 2) {
      int col1 = colb + tp * 16;
      int col2 = col1 + 16;
      short8 b1 = za, b2 = za;
      if (quad < 2) {
        b1 = *(const short8*)&w2t[col1 * 16 + k8];
        b2 = *(const short8*)&w2t[col2 * 16 + k8];
      }
      float bb1 = g2b[col1] * LOG2E, bb2 = g2b[col2] * LOG2E;
      float4v c1 = {bb1, bb1, bb1, bb1};
      float4v c2 = {bb2, bb2, bb2, bb2};
      float4v s11 = __builtin_amdgcn_mfma_f32_16x16x32_bf16(a1, b1, c1, 0, 0, 0);
      float4v s21 = __builtin_amdgcn_mfma_f32_16x16x32_bf16(a2, b1, c1, 0, 0, 0);
      float4v s12 = __builtin_amdgcn_mfma_f32_16x16x32_bf16(a1, b2, c2, 0, 0, 0);
      float4v s22 = __builtin_amdgcn_mfma_f32_16x16x32_bf16(a2, b2, c2, 0, 0, 0);
#pragma unroll
      for (int r = 0; r < 4; r++) {
        sacc[r]     += EXP2F(s11[r]) + EXP2F(s12[r]);
        sacc[4 + r] += EXP2F(s21[r]) + EXP2F(s22[r]);
      }
    }
#pragma unroll
    for (int q = 0; q < 8; q++) {
      int rl = (q >> 2) * 16 + quad * 4 + (q & 3);  // C/D row = quad*4+reg (+16 for A2)
      pl[rl * 128 + wave * 16 + n] = sacc[q];
    }
  }
  __syncthreads();
  if (t < 256) {
    int r = t >> 3, seg = t & 7;
    int base = r * 128 + seg * 16;
    float ll = 0.0f;
#pragma unroll
    for (int i = 0; i < 16; i++) ll += pl[base + i];
    sl[r * 8 + seg] = ll;
  }
  __syncthreads();
  if (t < 32) {
    float ll = 0.0f;
#pragma unroll
    for (int i = 0; i < 8; i++) ll += sl[t * 8 + i];
    out[256 + rowbase + t] = myMean - __logf(ll);  // ll = sum exp(s)
  }
}

extern "C" void kernel_launch(void* const* d_in, const int* in_sizes, int n_in,
                              void* d_out, int out_size, void* d_ws, size_t ws_size,
                              hipStream_t stream) {
  const float* x     = (const float*)d_in[0];
  const float* x_msg = (const float*)d_in[1];
  const int*   edges = (const int*)d_in[2];
  const int*   action= (const int*)d_in[3];
  const float* c1w   = (const float*)d_in[4];
  const float* c1b   = (const float*)d_in[5];
  const float* c2w   = (const float*)d_in[6];
  const float* c2b   = (const float*)d_in[7];
  const float* fcw   = (const float*)d_in[8];
  const float* fcb   = (const float*)d_in[9];
  const float* muw   = (const float*)d_in[10];
  const float* mub   = (const float*)d_in[11];
  const float* msgw  = (const float*)d_in[12];
  const float* msgb  = (const float*)d_in[13];
  const float* g1w   = (const float*)d_in[14];
  const float* g1b   = (const float*)d_in[15];
  const float* g2w   = (const float*)d_in[16];
  const float* g2b   = (const float*)d_in[17];
  float* out = (float*)d_out;  // reference outputs are fp32

  float* ws     = (float*)d_ws;
  unsigned short* h1024bf = (unsigned short*)ws;            // 262144 bf16
  unsigned short* fcwbf   = (unsigned short*)(ws + 131072); // 524288 bf16
  float* hidden = ws + 393216;           // 131072
  float* es2    = ws + 524288;           // 8192
  float* dinv   = ws + 532480;           // 8192
  float* xs2    = ws + 540672;           // 8192
  float* gbuf2  = ws + 548864;           // 131072
  float* wpart  = ws + 679936;           // 8704
  unsigned short* w2t = (unsigned short*)(ws + 688640);     // 131072 bf16
  int*   cnt2   = (int*)(ws + 754176);   // 16384
  int*   csr    = (int*)(ws + 770560);   // 1048576  -> total ~7.3 MB

  k_init<<<64, 256, 0, stream>>>(action, cnt2, out);
  k_prep<<<512, 512, 0, stream>>>(edges, fcw, g2w, g2b, fcwbf, w2t, wpart, cnt2, csr);
  k_conv<<<512, 512, 0, stream>>>(x, c1w, c1b, c2w, c2b, h1024bf);
  k_fc  <<<512, 256, 0, stream>>>(cnt2, x_msg, h1024bf, fcwbf, fcb, hidden, dinv, xs2);
  k_he  <<<512, 512, 0, stream>>>(hidden, muw, mub, msgw, msgb, dinv, es2, out);
  k_g1  <<<512, 512, 0, stream>>>(cnt2, csr, dinv, xs2, es2, g1w, g1b, gbuf2);
  k_msg <<<256, 512, 0, stream>>>(cnt2, csr, dinv, gbuf2, wpart, w2t, g2b, out);
}